// Round 3
// baseline (959.989 us; speedup 1.0000x reference)
//
#include <hip/hip_runtime.h>
#include <hip/hip_bf16.h>
#include <stdint.h>

#define O_N 100000
#define T_N 400000
#define NCH1 1563   // ceil(400000/256)
#define NCH3 391    // ceil(100000/256)

typedef __attribute__((ext_vector_type(8))) short short8;
typedef __attribute__((ext_vector_type(4))) float f32x4;
typedef __attribute__((ext_vector_type(16))) float f32x16;
typedef unsigned short ushort_t;

__device__ __forceinline__ unsigned short f2bf(float x) {
    union { float f; unsigned u; } v; v.f = x;
    unsigned u = v.u;
    unsigned rounded = u + 0x7FFF + ((u >> 16) & 1);
    return (unsigned short)(rounded >> 16);
}

__device__ __forceinline__ short8 pack8(f32x4 a, f32x4 b) {
    short8 t;
    t[0] = (short)f2bf(a[0]); t[1] = (short)f2bf(a[1]);
    t[2] = (short)f2bf(a[2]); t[3] = (short)f2bf(a[3]);
    t[4] = (short)f2bf(b[0]); t[5] = (short)f2bf(b[1]);
    t[6] = (short)f2bf(b[2]); t[7] = (short)f2bf(b[3]);
    return t;
}

// ---------------- 32x32x16 path ----------------
// B-fragment pack for mfma_f32_32x32x16_bf16:
// out[((ks*NT+nt)*64+lane)*8+j] = bf16(W[ks*16 + (lane>>5)*8 + j][col0 + nt*32 + (lane&31)])
__global__ void pack_b32(const float* __restrict__ W, ushort_t* __restrict__ out,
                         int Ksteps, int NT, int ldw, int col0) {
    int idx = blockIdx.x * 256 + threadIdx.x;
    int total = Ksteps * NT * 512;
    if (idx >= total) return;
    int j = idx & 7;
    int lane = (idx >> 3) & 63;
    int t2 = idx >> 9;
    int nt = t2 % NT;
    int ks = t2 / NT;
    int k = ks * 16 + ((lane >> 5) << 3) + j;
    int n = col0 + (nt << 5) + (lane & 31);
    out[idx] = f2bf(W[(size_t)k * ldw + n]);
}

// K1: gather [obj[s]|pred|obj[o]] per-lane -> A-frags, W1a resident in LDS, h -> hbuf (bf16).
__global__ __launch_bounds__(512, 2) void gemm1_k(
    const float* __restrict__ obj_vecs, const float* __restrict__ pred_vecs,
    const int* __restrict__ edges,
    const ushort_t* __restrict__ W1a_p, const float* __restrict__ b1a,
    ushort_t* __restrict__ hbuf, float* __restrict__ counts)
{
    __shared__ __align__(16) ushort_t Wl[49152]; // 96 KB
    const int tid = threadIdx.x;
    const int l = tid & 63;
    const int w = tid >> 6;          // 8 waves, 32 rows each
    const int q = l >> 5;
    const int r32 = l & 31;

    {
        const short8* s = reinterpret_cast<const short8*>(W1a_p);
        short8* d = reinterpret_cast<short8*>(Wl);
        #pragma unroll
        for (int i = 0; i < 12; ++i) d[i * 512 + tid] = s[i * 512 + tid];
    }
    __syncthreads();

    float bias[4];
    #pragma unroll
    for (int nt = 0; nt < 4; ++nt) bias[nt] = b1a[(nt << 5) + r32];

    for (int c = blockIdx.x; c < NCH1; c += gridDim.x) {
        int trow = c * 256 + w * 32 + r32;
        bool valid = trow < T_N;
        int tr = valid ? trow : T_N - 1;
        int2 e = ((const int2*)edges)[tr];
        if (valid && q == 0) {
            atomicAdd(&counts[e.x], 1.0f);
            atomicAdd(&counts[e.y], 1.0f);
        }
        const float* ps = obj_vecs  + (size_t)e.x * 128;
        const float* pp = pred_vecs + (size_t)tr * 128;
        const float* po = obj_vecs  + (size_t)e.y * 128;

        short8 af[24];
        #pragma unroll
        for (int ks = 0; ks < 24; ++ks) {
            const float* base = (ks < 8) ? ps : (ks < 16) ? pp : po;
            int colf = ((ks & 7) << 4) + (q << 3);
            f32x4 v0 = *reinterpret_cast<const f32x4*>(base + colf);
            f32x4 v1 = *reinterpret_cast<const f32x4*>(base + colf + 4);
            af[ks] = pack8(v0, v1);
        }

        f32x16 acc[4] = {};
        #pragma unroll
        for (int ks = 0; ks < 24; ++ks) {
            #pragma unroll
            for (int nt = 0; nt < 4; ++nt) {
                short8 bf = *reinterpret_cast<const short8*>(&Wl[(((ks << 2) + nt) * 64 + l) * 8]);
                acc[nt] = __builtin_amdgcn_mfma_f32_32x32x16_bf16(af[ks], bf, acc[nt], 0, 0, 0);
            }
        }

        #pragma unroll
        for (int nt = 0; nt < 4; ++nt) {
            #pragma unroll
            for (int r = 0; r < 16; ++r) {
                int rl = (r & 3) + ((r >> 2) << 3) + (q << 2);
                int trow2 = c * 256 + w * 32 + rl;
                if (trow2 < T_N) {
                    float hv = acc[nt][r] + bias[nt];
                    hv = fmaxf(hv, 0.0f);
                    hbuf[(size_t)trow2 * 128 + (nt << 5) + r32] = f2bf(hv);
                }
            }
        }
    }
}

// K2: h @ W1b + b1b -> split {new_s atomic, new_p store, new_o atomic}. W1b resident in LDS.
__global__ __launch_bounds__(512, 2) void gemm2_k(
    const ushort_t* __restrict__ hbuf, const int* __restrict__ edges,
    const ushort_t* __restrict__ W1b_p, const float* __restrict__ b1b,
    float* __restrict__ pooled, float* __restrict__ new_p)
{
    __shared__ __align__(16) ushort_t Wl[49152]; // 96 KB
    const int tid = threadIdx.x;
    const int l = tid & 63;
    const int w = tid >> 6;
    const int q = l >> 5;
    const int r32 = l & 31;

    {
        const short8* s = reinterpret_cast<const short8*>(W1b_p);
        short8* d = reinterpret_cast<short8*>(Wl);
        #pragma unroll
        for (int i = 0; i < 12; ++i) d[i * 512 + tid] = s[i * 512 + tid];
    }
    __syncthreads();

    float bias[12];
    #pragma unroll
    for (int nt = 0; nt < 12; ++nt) bias[nt] = b1b[(nt << 5) + r32];

    for (int c = blockIdx.x; c < NCH1; c += gridDim.x) {
        int trow = c * 256 + w * 32 + r32;
        int tr = trow < T_N ? trow : T_N - 1;

        short8 af[8];
        #pragma unroll
        for (int ks = 0; ks < 8; ++ks)
            af[ks] = *reinterpret_cast<const short8*>(&hbuf[(size_t)tr * 128 + (ks << 4) + (q << 3)]);

        #pragma unroll
        for (int half = 0; half < 2; ++half) {
            f32x16 acc[6] = {};
            #pragma unroll
            for (int ks = 0; ks < 8; ++ks) {
                #pragma unroll
                for (int nt2 = 0; nt2 < 6; ++nt2) {
                    int nt = half * 6 + nt2;
                    short8 bf = *reinterpret_cast<const short8*>(&Wl[((ks * 12 + nt) * 64 + l) * 8]);
                    acc[nt2] = __builtin_amdgcn_mfma_f32_32x32x16_bf16(af[ks], bf, acc[nt2], 0, 0, 0);
                }
            }
            #pragma unroll
            for (int r = 0; r < 16; ++r) {
                int rl = (r & 3) + ((r >> 2) << 3) + (q << 2);
                int trow2 = c * 256 + w * 32 + rl;
                if (trow2 < T_N) {
                    int2 e = ((const int2*)edges)[trow2];
                    #pragma unroll
                    for (int nt2 = 0; nt2 < 6; ++nt2) {
                        int nt = half * 6 + nt2;
                        float val = acc[nt2][r] + bias[nt];
                        if (nt < 4) {
                            atomicAdd(&pooled[(size_t)e.x * 128 + (nt << 5) + r32], val);
                        } else if (nt < 8) {
                            new_p[(size_t)trow2 * 128 + ((nt - 4) << 5) + r32] = val;
                        } else {
                            atomicAdd(&pooled[(size_t)e.y * 128 + ((nt - 8) << 5) + r32], val);
                        }
                    }
                }
            }
        }
    }
}

// K3: pooled/counts -> relu(x@W2a+b2a)@W2b+b2b, in place. Both weights resident in LDS.
__global__ __launch_bounds__(512, 2) void objects_k32(
    const float* __restrict__ counts,
    const ushort_t* __restrict__ W2a_p, const float* __restrict__ b2a,
    const ushort_t* __restrict__ W2b_p, const float* __restrict__ b2b,
    float* __restrict__ inout)
{
    __shared__ __align__(16) ushort_t Wa[16384];   // 32 KB
    __shared__ __align__(16) ushort_t Wb[16384];   // 32 KB
    __shared__ __align__(16) ushort_t hx[8][4096]; // 64 KB, per-wave swizzled exchange
    const int tid = threadIdx.x;
    const int l = tid & 63;
    const int w = tid >> 6;
    const int q = l >> 5;
    const int r32 = l & 31;

    {
        const short8* sa = reinterpret_cast<const short8*>(W2a_p);
        const short8* sb = reinterpret_cast<const short8*>(W2b_p);
        short8* da = reinterpret_cast<short8*>(Wa);
        short8* db = reinterpret_cast<short8*>(Wb);
        #pragma unroll
        for (int i = 0; i < 4; ++i) { da[i * 512 + tid] = sa[i * 512 + tid]; db[i * 512 + tid] = sb[i * 512 + tid]; }
    }
    __syncthreads();

    float ba[4], bb[4];
    #pragma unroll
    for (int nt = 0; nt < 4; ++nt) { ba[nt] = b2a[(nt << 5) + r32]; bb[nt] = b2b[(nt << 5) + r32]; }

    for (int c = blockIdx.x; c < NCH3; c += gridDim.x) {
        int row = c * 256 + w * 32 + r32;
        int rr = row < O_N ? row : O_N - 1;
        float inv = 1.0f / fmaxf(counts[rr], 1.0f);

        short8 af[8];
        #pragma unroll
        for (int ks = 0; ks < 8; ++ks) {
            f32x4 v0 = *reinterpret_cast<const f32x4*>(&inout[(size_t)rr * 128 + (ks << 4) + (q << 3)]);
            f32x4 v1 = *reinterpret_cast<const f32x4*>(&inout[(size_t)rr * 128 + (ks << 4) + (q << 3) + 4]);
            v0[0] *= inv; v0[1] *= inv; v0[2] *= inv; v0[3] *= inv;
            v1[0] *= inv; v1[1] *= inv; v1[2] *= inv; v1[3] *= inv;
            af[ks] = pack8(v0, v1);
        }

        f32x16 acc[4] = {};
        #pragma unroll
        for (int ks = 0; ks < 8; ++ks) {
            #pragma unroll
            for (int nt = 0; nt < 4; ++nt) {
                short8 bf = *reinterpret_cast<const short8*>(&Wa[(((ks << 2) + nt) * 64 + l) * 8]);
                acc[nt] = __builtin_amdgcn_mfma_f32_32x32x16_bf16(af[ks], bf, acc[nt], 0, 0, 0);
            }
        }

        // h -> per-wave LDS (XOR-swizzled rows to avoid 32-way conflicts on b128 reads)
        char* hxw = (char*)&hx[w][0];
        #pragma unroll
        for (int nt = 0; nt < 4; ++nt) {
            #pragma unroll
            for (int r = 0; r < 16; ++r) {
                int rl = (r & 3) + ((r >> 2) << 3) + (q << 2);
                float hv = fmaxf(acc[nt][r] + ba[nt], 0.0f);
                int off = rl * 256 + (((nt << 5) + r32) << 1);
                off ^= (rl & 15) << 4;
                *(ushort_t*)(hxw + off) = f2bf(hv);
            }
        }
        __syncthreads();

        short8 af2[8];
        #pragma unroll
        for (int ks = 0; ks < 8; ++ks) {
            int off = r32 * 256 + (ks << 5) + (q << 4);
            off ^= (r32 & 15) << 4;
            af2[ks] = *reinterpret_cast<const short8*>(hxw + off);
        }

        f32x16 acc2[4] = {};
        #pragma unroll
        for (int ks = 0; ks < 8; ++ks) {
            #pragma unroll
            for (int nt = 0; nt < 4; ++nt) {
                short8 bf = *reinterpret_cast<const short8*>(&Wb[(((ks << 2) + nt) * 64 + l) * 8]);
                acc2[nt] = __builtin_amdgcn_mfma_f32_32x32x16_bf16(af2[ks], bf, acc2[nt], 0, 0, 0);
            }
        }

        #pragma unroll
        for (int nt = 0; nt < 4; ++nt) {
            #pragma unroll
            for (int r = 0; r < 16; ++r) {
                int rl = (r & 3) + ((r >> 2) << 3) + (q << 2);
                int row2 = c * 256 + w * 32 + rl;
                if (row2 < O_N) inout[(size_t)row2 * 128 + (nt << 5) + r32] = acc2[nt][r] + bb[nt];
            }
        }
        __syncthreads();
    }
}

// ---------------- fallback path (round-1, 16x16x32, known-good) ----------------
__global__ void pack_b(const float* __restrict__ W, unsigned short* __restrict__ out,
                       int K, int Ntiles, int ldw, int col0) {
    int idx = blockIdx.x * 256 + threadIdx.x;
    int total = K * Ntiles * 16;
    if (idx >= total) return;
    int j = idx & 7;
    int lane = (idx >> 3) & 63;
    int t2 = idx >> 9;
    int ntile = t2 % Ntiles;
    int kstep = t2 / Ntiles;
    int k = kstep * 32 + ((lane >> 4) << 3) + j;
    int n = (ntile << 4) + (lane & 15);
    out[idx] = f2bf(W[(size_t)k * ldw + col0 + n]);
}

__device__ __forceinline__ void stage_w(const unsigned short* __restrict__ src,
                                        unsigned short* __restrict__ dst, int tid) {
    const short8* s = reinterpret_cast<const short8*>(src);
    short8* d = reinterpret_cast<short8*>(dst);
    d[tid] = s[tid];
    d[tid + 256] = s[tid + 256];
}

__global__ __launch_bounds__(256, 2) void triples_kernel(
    const float* __restrict__ obj_vecs, const float* __restrict__ pred_vecs,
    const int* __restrict__ edges,
    const unsigned short* __restrict__ W1a_p, const float* __restrict__ b1a,
    const unsigned short* __restrict__ W1b_p, const float* __restrict__ b1b,
    float* __restrict__ pooled, float* __restrict__ new_p, float* __restrict__ counts)
{
    __shared__ __align__(16) unsigned short Apack[24576];
    __shared__ __align__(16) unsigned short Wbuf[2][4096];
    __shared__ int sseg[64], oseg[64];
    const int tid = threadIdx.x;
    const int lane = tid & 63;
    const int w = tid >> 6;
    const int t0 = blockIdx.x * 64;
    if (tid < 64) {
        int s = edges[2 * (t0 + tid)];
        int o = edges[2 * (t0 + tid) + 1];
        sseg[tid] = s; oseg[tid] = o;
        atomicAdd(&counts[s], 1.0f);
        atomicAdd(&counts[o], 1.0f);
    }
    __syncthreads();
    for (int it = 0; it < 24; ++it) {
        int idx = it * 256 + tid;
        int r = idx / 96;
        int c = (idx % 96) * 4;
        const float* srcp;
        if (c < 128)      srcp = obj_vecs  + (size_t)sseg[r] * 128 + c;
        else if (c < 256) srcp = pred_vecs + (size_t)(t0 + r) * 128 + (c - 128);
        else              srcp = obj_vecs  + (size_t)oseg[r] * 128 + (c - 256);
        f32x4 v = *reinterpret_cast<const f32x4*>(srcp);
        int off = (((r >> 4) * 12 + (c >> 5)) << 9)
                + (((r & 15) | (((c & 31) >> 3) << 4)) << 3) + (c & 7);
        Apack[off + 0] = f2bf(v[0]); Apack[off + 1] = f2bf(v[1]);
        Apack[off + 2] = f2bf(v[2]); Apack[off + 3] = f2bf(v[3]);
    }
    stage_w(W1a_p, Wbuf[0], tid);
    __syncthreads();
    f32x4 acc[8];
    #pragma unroll
    for (int n = 0; n < 8; ++n) acc[n] = (f32x4){0.f, 0.f, 0.f, 0.f};
    for (int kk = 0; kk < 12; ++kk) {
        if (kk < 11) stage_w(W1a_p + (kk + 1) * 4096, Wbuf[(kk + 1) & 1], tid);
        short8 a = *reinterpret_cast<const short8*>(&Apack[((w * 12 + kk) << 9) + (lane << 3)]);
        const unsigned short* wb = Wbuf[kk & 1];
        #pragma unroll
        for (int n = 0; n < 8; ++n) {
            short8 b = *reinterpret_cast<const short8*>(&wb[((n << 6) + lane) << 3]);
            acc[n] = __builtin_amdgcn_mfma_f32_16x16x32_bf16(a, b, acc[n], 0, 0, 0);
        }
        __syncthreads();
    }
    #pragma unroll
    for (int n = 0; n < 8; ++n) {
        int col = (n << 4) + (lane & 15);
        float bias = b1a[col];
        int base = ((w * 4 + (col >> 5)) << 9) + (col & 7);
        int chi = ((col & 31) >> 3) << 4;
        #pragma unroll
        for (int jj = 0; jj < 4; ++jj) {
            int rloc = ((lane >> 4) << 2) + jj;
            float hv = acc[n][jj] + bias;
            hv = hv > 0.f ? hv : 0.f;
            Apack[base + ((rloc | chi) << 3)] = f2bf(hv);
        }
    }
    for (int g = 0; g < 3; ++g) {
        const unsigned short* Wsrc = W1b_p + g * 16384;
        stage_w(Wsrc, Wbuf[0], tid);
        __syncthreads();
        f32x4 acc2[8];
        #pragma unroll
        for (int n = 0; n < 8; ++n) acc2[n] = (f32x4){0.f, 0.f, 0.f, 0.f};
        for (int kk = 0; kk < 4; ++kk) {
            if (kk < 3) stage_w(Wsrc + (kk + 1) * 4096, Wbuf[(kk + 1) & 1], tid);
            short8 a = *reinterpret_cast<const short8*>(&Apack[((w * 4 + kk) << 9) + (lane << 3)]);
            const unsigned short* wb = Wbuf[kk & 1];
            #pragma unroll
            for (int n = 0; n < 8; ++n) {
                short8 b = *reinterpret_cast<const short8*>(&wb[((n << 6) + lane) << 3]);
                acc2[n] = __builtin_amdgcn_mfma_f32_16x16x32_bf16(a, b, acc2[n], 0, 0, 0);
            }
            __syncthreads();
        }
        #pragma unroll
        for (int n = 0; n < 8; ++n) {
            int col = (n << 4) + (lane & 15);
            float bias = b1b[g * 128 + col];
            #pragma unroll
            for (int jj = 0; jj < 4; ++jj) {
                int rloc = (w << 4) + ((lane >> 4) << 2) + jj;
                float val = acc2[n][jj] + bias;
                if (g == 1) {
                    new_p[(size_t)(t0 + rloc) * 128 + col] = val;
                } else {
                    int seg = (g == 0) ? sseg[rloc] : oseg[rloc];
                    atomicAdd(&pooled[(size_t)seg * 128 + col], val);
                }
            }
        }
    }
}

__global__ __launch_bounds__(256, 2) void objects_kernel(
    const float* __restrict__ counts,
    const unsigned short* __restrict__ W2a_p, const float* __restrict__ b2a,
    const unsigned short* __restrict__ W2b_p, const float* __restrict__ b2b,
    float* __restrict__ inout)
{
    __shared__ __align__(16) unsigned short Apack[8192];
    __shared__ __align__(16) unsigned short Hpack[8192];
    __shared__ __align__(16) unsigned short Wbuf[2][4096];
    const int tid = threadIdx.x;
    const int lane = tid & 63;
    const int w = tid >> 6;
    const int r0 = blockIdx.x * 64;
    for (int it = 0; it < 8; ++it) {
        int idx = it * 256 + tid;
        int r = idx >> 5;
        int c = (idx & 31) << 2;
        int row = r0 + r;
        float vals[4] = {0.f, 0.f, 0.f, 0.f};
        if (row < O_N) {
            f32x4 v = *reinterpret_cast<const f32x4*>(&inout[(size_t)row * 128 + c]);
            float inv = 1.0f / fmaxf(counts[row], 1.0f);
            vals[0] = v[0] * inv; vals[1] = v[1] * inv;
            vals[2] = v[2] * inv; vals[3] = v[3] * inv;
        }
        int off = (((r >> 4) * 4 + (c >> 5)) << 9)
                + (((r & 15) | (((c & 31) >> 3) << 4)) << 3) + (c & 7);
        Apack[off + 0] = f2bf(vals[0]); Apack[off + 1] = f2bf(vals[1]);
        Apack[off + 2] = f2bf(vals[2]); Apack[off + 3] = f2bf(vals[3]);
    }
    stage_w(W2a_p, Wbuf[0], tid);
    __syncthreads();
    f32x4 acc[8];
    #pragma unroll
    for (int n = 0; n < 8; ++n) acc[n] = (f32x4){0.f, 0.f, 0.f, 0.f};
    for (int kk = 0; kk < 4; ++kk) {
        if (kk < 3) stage_w(W2a_p + (kk + 1) * 4096, Wbuf[(kk + 1) & 1], tid);
        short8 a = *reinterpret_cast<const short8*>(&Apack[((w * 4 + kk) << 9) + (lane << 3)]);
        const unsigned short* wb = Wbuf[kk & 1];
        #pragma unroll
        for (int n = 0; n < 8; ++n) {
            short8 b = *reinterpret_cast<const short8*>(&wb[((n << 6) + lane) << 3]);
            acc[n] = __builtin_amdgcn_mfma_f32_16x16x32_bf16(a, b, acc[n], 0, 0, 0);
        }
        __syncthreads();
    }
    #pragma unroll
    for (int n = 0; n < 8; ++n) {
        int col = (n << 4) + (lane & 15);
        float bias = b2a[col];
        int base = ((w * 4 + (col >> 5)) << 9) + (col & 7);
        int chi = ((col & 31) >> 3) << 4;
        #pragma unroll
        for (int jj = 0; jj < 4; ++jj) {
            int rloc = ((lane >> 4) << 2) + jj;
            float hv = acc[n][jj] + bias;
            hv = hv > 0.f ? hv : 0.f;
            Hpack[base + ((rloc | chi) << 3)] = f2bf(hv);
        }
    }
    stage_w(W2b_p, Wbuf[0], tid);
    __syncthreads();
    f32x4 acc2[8];
    #pragma unroll
    for (int n = 0; n < 8; ++n) acc2[n] = (f32x4){0.f, 0.f, 0.f, 0.f};
    for (int kk = 0; kk < 4; ++kk) {
        if (kk < 3) stage_w(W2b_p + (kk + 1) * 4096, Wbuf[(kk + 1) & 1], tid);
        short8 a = *reinterpret_cast<const short8*>(&Hpack[((w * 4 + kk) << 9) + (lane << 3)]);
        const unsigned short* wb = Wbuf[kk & 1];
        #pragma unroll
        for (int n = 0; n < 8; ++n) {
            short8 b = *reinterpret_cast<const short8*>(&wb[((n << 6) + lane) << 3]);
            acc2[n] = __builtin_amdgcn_mfma_f32_16x16x32_bf16(a, b, acc2[n], 0, 0, 0);
        }
        __syncthreads();
    }
    #pragma unroll
    for (int n = 0; n < 8; ++n) {
        int col = (n << 4) + (lane & 15);
        float bias = b2b[n ? (n << 4) + (lane & 15) : (lane & 15)];
        #pragma unroll
        for (int jj = 0; jj < 4; ++jj) {
            int rloc = (w << 4) + ((lane >> 4) << 2) + jj;
            int row = r0 + rloc;
            if (row < O_N) inout[(size_t)row * 128 + col] = acc2[n][jj] + bias;
        }
    }
}

extern "C" void kernel_launch(void* const* d_in, const int* in_sizes, int n_in,
                              void* d_out, int out_size, void* d_ws, size_t ws_size,
                              hipStream_t stream)
{
    const float* obj   = (const float*)d_in[0];
    const float* pred  = (const float*)d_in[1];
    const int*   edges = (const int*)d_in[2];
    const float* W1a = (const float*)d_in[3];
    const float* b1a = (const float*)d_in[4];
    const float* W1b = (const float*)d_in[5];
    const float* b1b = (const float*)d_in[6];
    const float* W2a = (const float*)d_in[7];
    const float* b2a = (const float*)d_in[8];
    const float* W2b = (const float*)d_in[9];
    const float* b2b = (const float*)d_in[10];

    float* out    = (float*)d_out;
    float* pooled = out;                       // O x 128, accumulated then overwritten by new_obj
    float* new_p  = out + (size_t)O_N * 128;   // T x 128

    uintptr_t wsbase = (uintptr_t)d_ws;
    float* counts = (float*)wsbase;
    uintptr_t p = (wsbase + (size_t)O_N * 4 + 255) & ~(uintptr_t)255;
    ushort_t* W1a_p = (ushort_t*)p;  p += (size_t)49152 * 2;
    ushort_t* W1b_p = (ushort_t*)p;  p += (size_t)49152 * 2;
    ushort_t* W2a_p = (ushort_t*)p;  p += (size_t)16384 * 2;
    ushort_t* W2b_p = (ushort_t*)p;  p += (size_t)16384 * 2;
    ushort_t* hbuf  = (ushort_t*)p;
    size_t need = (p - wsbase) + (size_t)T_N * 128 * 2;

    hipMemsetAsync(pooled, 0, (size_t)O_N * 128 * sizeof(float), stream);
    hipMemsetAsync(counts, 0, (size_t)O_N * sizeof(float), stream);

    if (ws_size >= need) {
        // 32x32x16 path: resident-weight, barrier-free GEMM kernels
        // grids sized to total = Ksteps*NT*512 elements / 256 threads (round-2 bug: was half)
        pack_b32<<<192, 256, 0, stream>>>(W1a, W1a_p, 24, 4, 128, 0);   // 49152 items
        pack_b32<<<192, 256, 0, stream>>>(W1b, W1b_p, 8, 12, 384, 0);   // 49152 items
        pack_b32<<<64, 256, 0, stream>>>(W2a, W2a_p, 8, 4, 128, 0);     // 16384 items
        pack_b32<<<64, 256, 0, stream>>>(W2b, W2b_p, 8, 4, 128, 0);     // 16384 items

        gemm1_k<<<521, 512, 0, stream>>>(obj, pred, edges, W1a_p, b1a, hbuf, counts);
        gemm2_k<<<521, 512, 0, stream>>>(hbuf, edges, W1b_p, b1b, pooled, new_p);
        objects_k32<<<391, 512, 0, stream>>>(counts, W2a_p, b2a, W2b_p, b2b, out);
    } else {
        // fallback: round-1 fused path (correct, slower)
        pack_b<<<192, 256, 0, stream>>>(W1a, W1a_p, 384, 8, 128, 0);
        pack_b<<<64, 256, 0, stream>>>(W1b, W1b_p,         128, 8, 384, 0);
        pack_b<<<64, 256, 0, stream>>>(W1b, W1b_p + 16384, 128, 8, 384, 128);
        pack_b<<<64, 256, 0, stream>>>(W1b, W1b_p + 32768, 128, 8, 384, 256);
        pack_b<<<64, 256, 0, stream>>>(W2a, W2a_p, 128, 8, 128, 0);
        pack_b<<<64, 256, 0, stream>>>(W2b, W2b_p, 128, 8, 128, 0);

        triples_kernel<<<T_N / 64, 256, 0, stream>>>(obj, pred, edges,
                                                     W1a_p, b1a, W1b_p, b1b,
                                                     pooled, new_p, counts);
        objects_kernel<<<(O_N + 63) / 64, 256, 0, stream>>>(counts, W2a_p, b2a, W2b_p, b2b, out);
    }
}

// Round 4
// 670.079 us; speedup vs baseline: 1.4327x; 1.4327x over previous
//
#include <hip/hip_runtime.h>
#include <hip/hip_bf16.h>
#include <stdint.h>

#define O_N 100000
#define T_N 400000
#define NCH1 1563   // ceil(400000/256)
#define NCH3 391    // ceil(100000/256)

typedef __attribute__((ext_vector_type(8))) short short8;
typedef __attribute__((ext_vector_type(4))) float f32x4;
typedef __attribute__((ext_vector_type(16))) float f32x16;
typedef unsigned short ushort_t;

__device__ __forceinline__ unsigned short f2bf(float x) {
    union { float f; unsigned u; } v; v.f = x;
    unsigned u = v.u;
    unsigned rounded = u + 0x7FFF + ((u >> 16) & 1);
    return (unsigned short)(rounded >> 16);
}

__device__ __forceinline__ short8 pack8(f32x4 a, f32x4 b) {
    short8 t;
    t[0] = (short)f2bf(a[0]); t[1] = (short)f2bf(a[1]);
    t[2] = (short)f2bf(a[2]); t[3] = (short)f2bf(a[3]);
    t[4] = (short)f2bf(b[0]); t[5] = (short)f2bf(b[1]);
    t[6] = (short)f2bf(b[2]); t[7] = (short)f2bf(b[3]);
    return t;
}

// ---------------- 32x32x16 path ----------------
// B-fragment pack for mfma_f32_32x32x16_bf16:
// out[((ks*NT+nt)*64+lane)*8+j] = bf16(W[ks*16 + (lane>>5)*8 + j][col0 + nt*32 + (lane&31)])
__global__ void pack_b32(const float* __restrict__ W, ushort_t* __restrict__ out,
                         int Ksteps, int NT, int ldw, int col0) {
    int idx = blockIdx.x * 256 + threadIdx.x;
    int total = Ksteps * NT * 512;
    if (idx >= total) return;
    int j = idx & 7;
    int lane = (idx >> 3) & 63;
    int t2 = idx >> 9;
    int nt = t2 % NT;
    int ks = t2 / NT;
    int k = ks * 16 + ((lane >> 5) << 3) + j;
    int n = col0 + (nt << 5) + (lane & 31);
    out[idx] = f2bf(W[(size_t)k * ldw + n]);
}

__device__ __forceinline__ short8 ldrow(const float* __restrict__ base, int k8, int q) {
    int colf = (k8 << 4) + (q << 3);
    f32x4 v0 = *reinterpret_cast<const f32x4*>(base + colf);
    f32x4 v1 = *reinterpret_cast<const f32x4*>(base + colf + 4);
    return pack8(v0, v1);
}

// K1: gather [obj[s]|pred|obj[o]] per-lane -> A-frags (2-group register dbuf, no spill),
// W1a resident in LDS, h -> hbuf (bf16).
__global__ __launch_bounds__(512, 2) void gemm1_k(
    const float* __restrict__ obj_vecs, const float* __restrict__ pred_vecs,
    const int* __restrict__ edges,
    const ushort_t* __restrict__ W1a_p, const float* __restrict__ b1a,
    ushort_t* __restrict__ hbuf, float* __restrict__ counts)
{
    __shared__ __align__(16) ushort_t Wl[49152]; // 96 KB
    const int tid = threadIdx.x;
    const int l = tid & 63;
    const int w = tid >> 6;          // 8 waves, 32 rows each
    const int q = l >> 5;
    const int r32 = l & 31;

    {
        const short8* s = reinterpret_cast<const short8*>(W1a_p);
        short8* d = reinterpret_cast<short8*>(Wl);
        #pragma unroll
        for (int i = 0; i < 12; ++i) d[i * 512 + tid] = s[i * 512 + tid];
    }
    __syncthreads();

    float bias[4];
    #pragma unroll
    for (int nt = 0; nt < 4; ++nt) bias[nt] = b1a[(nt << 5) + r32];

    for (int c = blockIdx.x; c < NCH1; c += gridDim.x) {
        int trow = c * 256 + w * 32 + r32;
        bool valid = trow < T_N;
        int tr = valid ? trow : T_N - 1;
        int2 e = ((const int2*)edges)[tr];
        if (valid && q == 0) {
            atomicAdd(&counts[e.x], 1.0f);
            atomicAdd(&counts[e.y], 1.0f);
        }
        const float* ps = obj_vecs  + (size_t)e.x * 128;
        const float* pp = pred_vecs + (size_t)tr * 128;
        const float* po = obj_vecs  + (size_t)e.y * 128;

        short8 afA[8], afB[8];
        #pragma unroll
        for (int k8 = 0; k8 < 8; ++k8) afA[k8] = ldrow(ps, k8, q);
        #pragma unroll
        for (int k8 = 0; k8 < 8; ++k8) afB[k8] = ldrow(pp, k8, q);

        f32x16 acc[4] = {};
        #pragma unroll
        for (int k8 = 0; k8 < 8; ++k8) {
            #pragma unroll
            for (int nt = 0; nt < 4; ++nt) {
                short8 bf = *reinterpret_cast<const short8*>(&Wl[(((k8 << 2) + nt) * 64 + l) * 8]);
                acc[nt] = __builtin_amdgcn_mfma_f32_32x32x16_bf16(afA[k8], bf, acc[nt], 0, 0, 0);
            }
        }
        #pragma unroll
        for (int k8 = 0; k8 < 8; ++k8) afA[k8] = ldrow(po, k8, q);
        #pragma unroll
        for (int k8 = 0; k8 < 8; ++k8) {
            #pragma unroll
            for (int nt = 0; nt < 4; ++nt) {
                short8 bf = *reinterpret_cast<const short8*>(&Wl[((((8 + k8) << 2) + nt) * 64 + l) * 8]);
                acc[nt] = __builtin_amdgcn_mfma_f32_32x32x16_bf16(afB[k8], bf, acc[nt], 0, 0, 0);
            }
        }
        #pragma unroll
        for (int k8 = 0; k8 < 8; ++k8) {
            #pragma unroll
            for (int nt = 0; nt < 4; ++nt) {
                short8 bf = *reinterpret_cast<const short8*>(&Wl[((((16 + k8) << 2) + nt) * 64 + l) * 8]);
                acc[nt] = __builtin_amdgcn_mfma_f32_32x32x16_bf16(afA[k8], bf, acc[nt], 0, 0, 0);
            }
        }

        #pragma unroll
        for (int nt = 0; nt < 4; ++nt) {
            #pragma unroll
            for (int r = 0; r < 16; ++r) {
                int rl = (r & 3) + ((r >> 2) << 3) + (q << 2);
                int trow2 = c * 256 + w * 32 + rl;
                if (trow2 < T_N) {
                    float hv = fmaxf(acc[nt][r] + bias[nt], 0.0f);
                    hbuf[(size_t)trow2 * 128 + (nt << 5) + r32] = f2bf(hv);
                }
            }
        }
    }
}

// K2: h @ W1b + b1b -> 3 nt-groups: {new_s pk-atomic, new_p store, new_o pk-atomic}.
// W1b resident in LDS; pooled accumulated as bf16 via global_atomic_pk_add_bf16.
__global__ __launch_bounds__(512, 2) void gemm2_k(
    const ushort_t* __restrict__ hbuf, const int* __restrict__ edges,
    const ushort_t* __restrict__ W1b_p, const float* __restrict__ b1b,
    ushort_t* __restrict__ pooled_bf, float* __restrict__ new_p)
{
    __shared__ __align__(16) ushort_t Wl[49152]; // 96 KB
    const int tid = threadIdx.x;
    const int l = tid & 63;
    const int w = tid >> 6;
    const int q = l >> 5;
    const int r32 = l & 31;

    {
        const short8* s = reinterpret_cast<const short8*>(W1b_p);
        short8* d = reinterpret_cast<short8*>(Wl);
        #pragma unroll
        for (int i = 0; i < 12; ++i) d[i * 512 + tid] = s[i * 512 + tid];
    }
    __syncthreads();

    float bias[12];
    #pragma unroll
    for (int nt = 0; nt < 12; ++nt) bias[nt] = b1b[(nt << 5) + r32];

    for (int c = blockIdx.x; c < NCH1; c += gridDim.x) {
        int trow = c * 256 + w * 32 + r32;
        int tr = trow < T_N ? trow : T_N - 1;

        short8 af[8];
        #pragma unroll
        for (int ks = 0; ks < 8; ++ks)
            af[ks] = *reinterpret_cast<const short8*>(&hbuf[(size_t)tr * 128 + (ks << 4) + (q << 3)]);

        #pragma unroll
        for (int g = 0; g < 3; ++g) {
            f32x16 acc[4] = {};
            #pragma unroll
            for (int ks = 0; ks < 8; ++ks) {
                #pragma unroll
                for (int nt2 = 0; nt2 < 4; ++nt2) {
                    short8 bf = *reinterpret_cast<const short8*>(&Wl[((ks * 12 + (g << 2) + nt2) * 64 + l) * 8]);
                    acc[nt2] = __builtin_amdgcn_mfma_f32_32x32x16_bf16(af[ks], bf, acc[nt2], 0, 0, 0);
                }
            }
            if (g == 1) {
                #pragma unroll
                for (int nt2 = 0; nt2 < 4; ++nt2) {
                    #pragma unroll
                    for (int r = 0; r < 16; ++r) {
                        int rl = (r & 3) + ((r >> 2) << 3) + (q << 2);
                        int trow2 = c * 256 + w * 32 + rl;
                        if (trow2 < T_N)
                            new_p[(size_t)trow2 * 128 + (nt2 << 5) + r32] = acc[nt2][r] + bias[4 + nt2];
                    }
                }
            } else {
                #pragma unroll
                for (int r = 0; r < 16; ++r) {
                    int rl = (r & 3) + ((r >> 2) << 3) + (q << 2);
                    int trow2 = c * 256 + w * 32 + rl;
                    bool v2 = trow2 < T_N;
                    int t2 = v2 ? trow2 : T_N - 1;
                    int2 e2 = ((const int2*)edges)[t2];
                    int seg = (g == 0) ? e2.x : e2.y;
                    ushort_t* pb = pooled_bf + (size_t)seg * 128;
                    #pragma unroll
                    for (int nt2 = 0; nt2 < 4; ++nt2) {
                        float val = acc[nt2][r] + bias[(g << 2) + nt2];
                        float other = __shfl_xor(val, 1, 64);
                        if (v2 && !(r32 & 1)) {
                            unsigned dat = (unsigned)f2bf(val) | ((unsigned)f2bf(other) << 16);
                            uint64_t addr = (uint64_t)(uintptr_t)(pb + (nt2 << 5) + r32);
                            asm volatile("global_atomic_pk_add_bf16 %0, %1, off"
                                         :: "v"(addr), "v"(dat) : "memory");
                        }
                    }
                }
            }
        }
    }
}

// K3: pooled_bf/counts -> relu(x@W2a+b2a)@W2b+b2b -> new_obj (f32, d_out).
__global__ __launch_bounds__(512, 2) void objects_k32(
    const ushort_t* __restrict__ pooled_bf, const float* __restrict__ counts,
    const ushort_t* __restrict__ W2a_p, const float* __restrict__ b2a,
    const ushort_t* __restrict__ W2b_p, const float* __restrict__ b2b,
    float* __restrict__ outp)
{
    __shared__ __align__(16) ushort_t Wa[16384];   // 32 KB
    __shared__ __align__(16) ushort_t Wb[16384];   // 32 KB
    __shared__ __align__(16) ushort_t hx[8][4096]; // 64 KB, per-wave swizzled exchange
    const int tid = threadIdx.x;
    const int l = tid & 63;
    const int w = tid >> 6;
    const int q = l >> 5;
    const int r32 = l & 31;

    {
        const short8* sa = reinterpret_cast<const short8*>(W2a_p);
        const short8* sb = reinterpret_cast<const short8*>(W2b_p);
        short8* da = reinterpret_cast<short8*>(Wa);
        short8* db = reinterpret_cast<short8*>(Wb);
        #pragma unroll
        for (int i = 0; i < 4; ++i) { da[i * 512 + tid] = sa[i * 512 + tid]; db[i * 512 + tid] = sb[i * 512 + tid]; }
    }
    __syncthreads();

    float ba[4], bb[4];
    #pragma unroll
    for (int nt = 0; nt < 4; ++nt) { ba[nt] = b2a[(nt << 5) + r32]; bb[nt] = b2b[(nt << 5) + r32]; }

    for (int c = blockIdx.x; c < NCH3; c += gridDim.x) {
        int row = c * 256 + w * 32 + r32;
        int rr = row < O_N ? row : O_N - 1;
        float inv = 1.0f / fmaxf(counts[rr], 1.0f);

        short8 af[8];
        #pragma unroll
        for (int ks = 0; ks < 8; ++ks) {
            short8 raw = *reinterpret_cast<const short8*>(&pooled_bf[(size_t)rr * 128 + (ks << 4) + (q << 3)]);
            short8 a;
            #pragma unroll
            for (int j = 0; j < 8; ++j) {
                union { float f; unsigned u; } t;
                t.u = ((unsigned)(unsigned short)raw[j]) << 16;
                a[j] = (short)f2bf(t.f * inv);
            }
            af[ks] = a;
        }

        f32x16 acc[4] = {};
        #pragma unroll
        for (int ks = 0; ks < 8; ++ks) {
            #pragma unroll
            for (int nt = 0; nt < 4; ++nt) {
                short8 bf = *reinterpret_cast<const short8*>(&Wa[(((ks << 2) + nt) * 64 + l) * 8]);
                acc[nt] = __builtin_amdgcn_mfma_f32_32x32x16_bf16(af[ks], bf, acc[nt], 0, 0, 0);
            }
        }

        // h -> per-wave LDS (XOR-swizzled rows to avoid 32-way conflicts on b128 reads)
        char* hxw = (char*)&hx[w][0];
        #pragma unroll
        for (int nt = 0; nt < 4; ++nt) {
            #pragma unroll
            for (int r = 0; r < 16; ++r) {
                int rl = (r & 3) + ((r >> 2) << 3) + (q << 2);
                float hv = fmaxf(acc[nt][r] + ba[nt], 0.0f);
                int off = rl * 256 + (((nt << 5) + r32) << 1);
                off ^= (rl & 15) << 4;
                *(ushort_t*)(hxw + off) = f2bf(hv);
            }
        }
        __syncthreads();

        short8 af2[8];
        #pragma unroll
        for (int ks = 0; ks < 8; ++ks) {
            int off = r32 * 256 + (ks << 5) + (q << 4);
            off ^= (r32 & 15) << 4;
            af2[ks] = *reinterpret_cast<const short8*>(hxw + off);
        }

        f32x16 acc2[4] = {};
        #pragma unroll
        for (int ks = 0; ks < 8; ++ks) {
            #pragma unroll
            for (int nt = 0; nt < 4; ++nt) {
                short8 bf = *reinterpret_cast<const short8*>(&Wb[(((ks << 2) + nt) * 64 + l) * 8]);
                acc2[nt] = __builtin_amdgcn_mfma_f32_32x32x16_bf16(af2[ks], bf, acc2[nt], 0, 0, 0);
            }
        }

        #pragma unroll
        for (int nt = 0; nt < 4; ++nt) {
            #pragma unroll
            for (int r = 0; r < 16; ++r) {
                int rl = (r & 3) + ((r >> 2) << 3) + (q << 2);
                int row2 = c * 256 + w * 32 + rl;
                if (row2 < O_N) outp[(size_t)row2 * 128 + (nt << 5) + r32] = acc2[nt][r] + bb[nt];
            }
        }
        __syncthreads();
    }
}

// ---------------- fallback path (round-1, 16x16x32, known-good) ----------------
__global__ void pack_b(const float* __restrict__ W, unsigned short* __restrict__ out,
                       int K, int Ntiles, int ldw, int col0) {
    int idx = blockIdx.x * 256 + threadIdx.x;
    int total = K * Ntiles * 16;
    if (idx >= total) return;
    int j = idx & 7;
    int lane = (idx >> 3) & 63;
    int t2 = idx >> 9;
    int ntile = t2 % Ntiles;
    int kstep = t2 / Ntiles;
    int k = kstep * 32 + ((lane >> 4) << 3) + j;
    int n = (ntile << 4) + (lane & 15);
    out[idx] = f2bf(W[(size_t)k * ldw + col0 + n]);
}

__device__ __forceinline__ void stage_w(const unsigned short* __restrict__ src,
                                        unsigned short* __restrict__ dst, int tid) {
    const short8* s = reinterpret_cast<const short8*>(src);
    short8* d = reinterpret_cast<short8*>(dst);
    d[tid] = s[tid];
    d[tid + 256] = s[tid + 256];
}

__global__ __launch_bounds__(256, 2) void triples_kernel(
    const float* __restrict__ obj_vecs, const float* __restrict__ pred_vecs,
    const int* __restrict__ edges,
    const unsigned short* __restrict__ W1a_p, const float* __restrict__ b1a,
    const unsigned short* __restrict__ W1b_p, const float* __restrict__ b1b,
    float* __restrict__ pooled, float* __restrict__ new_p, float* __restrict__ counts)
{
    __shared__ __align__(16) unsigned short Apack[24576];
    __shared__ __align__(16) unsigned short Wbuf[2][4096];
    __shared__ int sseg[64], oseg[64];
    const int tid = threadIdx.x;
    const int lane = tid & 63;
    const int w = tid >> 6;
    const int t0 = blockIdx.x * 64;
    if (tid < 64) {
        int s = edges[2 * (t0 + tid)];
        int o = edges[2 * (t0 + tid) + 1];
        sseg[tid] = s; oseg[tid] = o;
        atomicAdd(&counts[s], 1.0f);
        atomicAdd(&counts[o], 1.0f);
    }
    __syncthreads();
    for (int it = 0; it < 24; ++it) {
        int idx = it * 256 + tid;
        int r = idx / 96;
        int c = (idx % 96) * 4;
        const float* srcp;
        if (c < 128)      srcp = obj_vecs  + (size_t)sseg[r] * 128 + c;
        else if (c < 256) srcp = pred_vecs + (size_t)(t0 + r) * 128 + (c - 128);
        else              srcp = obj_vecs  + (size_t)oseg[r] * 128 + (c - 256);
        f32x4 v = *reinterpret_cast<const f32x4*>(srcp);
        int off = (((r >> 4) * 12 + (c >> 5)) << 9)
                + (((r & 15) | (((c & 31) >> 3) << 4)) << 3) + (c & 7);
        Apack[off + 0] = f2bf(v[0]); Apack[off + 1] = f2bf(v[1]);
        Apack[off + 2] = f2bf(v[2]); Apack[off + 3] = f2bf(v[3]);
    }
    stage_w(W1a_p, Wbuf[0], tid);
    __syncthreads();
    f32x4 acc[8];
    #pragma unroll
    for (int n = 0; n < 8; ++n) acc[n] = (f32x4){0.f, 0.f, 0.f, 0.f};
    for (int kk = 0; kk < 12; ++kk) {
        if (kk < 11) stage_w(W1a_p + (kk + 1) * 4096, Wbuf[(kk + 1) & 1], tid);
        short8 a = *reinterpret_cast<const short8*>(&Apack[((w * 12 + kk) << 9) + (lane << 3)]);
        const unsigned short* wb = Wbuf[kk & 1];
        #pragma unroll
        for (int n = 0; n < 8; ++n) {
            short8 b = *reinterpret_cast<const short8*>(&wb[((n << 6) + lane) << 3]);
            acc[n] = __builtin_amdgcn_mfma_f32_16x16x32_bf16(a, b, acc[n], 0, 0, 0);
        }
        __syncthreads();
    }
    #pragma unroll
    for (int n = 0; n < 8; ++n) {
        int col = (n << 4) + (lane & 15);
        float bias = b1a[col];
        int base = ((w * 4 + (col >> 5)) << 9) + (col & 7);
        int chi = ((col & 31) >> 3) << 4;
        #pragma unroll
        for (int jj = 0; jj < 4; ++jj) {
            int rloc = ((lane >> 4) << 2) + jj;
            float hv = acc[n][jj] + bias;
            hv = hv > 0.f ? hv : 0.f;
            Apack[base + ((rloc | chi) << 3)] = f2bf(hv);
        }
    }
    for (int g = 0; g < 3; ++g) {
        const unsigned short* Wsrc = W1b_p + g * 16384;
        stage_w(Wsrc, Wbuf[0], tid);
        __syncthreads();
        f32x4 acc2[8];
        #pragma unroll
        for (int n = 0; n < 8; ++n) acc2[n] = (f32x4){0.f, 0.f, 0.f, 0.f};
        for (int kk = 0; kk < 4; ++kk) {
            if (kk < 3) stage_w(Wsrc + (kk + 1) * 4096, Wbuf[(kk + 1) & 1], tid);
            short8 a = *reinterpret_cast<const short8*>(&Apack[((w * 4 + kk) << 9) + (lane << 3)]);
            const unsigned short* wb = Wbuf[kk & 1];
            #pragma unroll
            for (int n = 0; n < 8; ++n) {
                short8 b = *reinterpret_cast<const short8*>(&wb[((n << 6) + lane) << 3]);
                acc2[n] = __builtin_amdgcn_mfma_f32_16x16x32_bf16(a, b, acc2[n], 0, 0, 0);
            }
            __syncthreads();
        }
        #pragma unroll
        for (int n = 0; n < 8; ++n) {
            int col = (n << 4) + (lane & 15);
            float bias = b1b[g * 128 + col];
            #pragma unroll
            for (int jj = 0; jj < 4; ++jj) {
                int rloc = (w << 4) + ((lane >> 4) << 2) + jj;
                float val = acc2[n][jj] + bias;
                if (g == 1) {
                    new_p[(size_t)(t0 + rloc) * 128 + col] = val;
                } else {
                    int seg = (g == 0) ? sseg[rloc] : oseg[rloc];
                    atomicAdd(&pooled[(size_t)seg * 128 + col], val);
                }
            }
        }
    }
}

__global__ __launch_bounds__(256, 2) void objects_kernel(
    const float* __restrict__ counts,
    const unsigned short* __restrict__ W2a_p, const float* __restrict__ b2a,
    const unsigned short* __restrict__ W2b_p, const float* __restrict__ b2b,
    float* __restrict__ inout)
{
    __shared__ __align__(16) unsigned short Apack[8192];
    __shared__ __align__(16) unsigned short Hpack[8192];
    __shared__ __align__(16) unsigned short Wbuf[2][4096];
    const int tid = threadIdx.x;
    const int lane = tid & 63;
    const int w = tid >> 6;
    const int r0 = blockIdx.x * 64;
    for (int it = 0; it < 8; ++it) {
        int idx = it * 256 + tid;
        int r = idx >> 5;
        int c = (idx & 31) << 2;
        int row = r0 + r;
        float vals[4] = {0.f, 0.f, 0.f, 0.f};
        if (row < O_N) {
            f32x4 v = *reinterpret_cast<const f32x4*>(&inout[(size_t)row * 128 + c]);
            float inv = 1.0f / fmaxf(counts[row], 1.0f);
            vals[0] = v[0] * inv; vals[1] = v[1] * inv;
            vals[2] = v[2] * inv; vals[3] = v[3] * inv;
        }
        int off = (((r >> 4) * 4 + (c >> 5)) << 9)
                + (((r & 15) | (((c & 31) >> 3) << 4)) << 3) + (c & 7);
        Apack[off + 0] = f2bf(vals[0]); Apack[off + 1] = f2bf(vals[1]);
        Apack[off + 2] = f2bf(vals[2]); Apack[off + 3] = f2bf(vals[3]);
    }
    stage_w(W2a_p, Wbuf[0], tid);
    __syncthreads();
    f32x4 acc[8];
    #pragma unroll
    for (int n = 0; n < 8; ++n) acc[n] = (f32x4){0.f, 0.f, 0.f, 0.f};
    for (int kk = 0; kk < 4; ++kk) {
        if (kk < 3) stage_w(W2a_p + (kk + 1) * 4096, Wbuf[(kk + 1) & 1], tid);
        short8 a = *reinterpret_cast<const short8*>(&Apack[((w * 4 + kk) << 9) + (lane << 3)]);
        const unsigned short* wb = Wbuf[kk & 1];
        #pragma unroll
        for (int n = 0; n < 8; ++n) {
            short8 b = *reinterpret_cast<const short8*>(&wb[((n << 6) + lane) << 3]);
            acc[n] = __builtin_amdgcn_mfma_f32_16x16x32_bf16(a, b, acc[n], 0, 0, 0);
        }
        __syncthreads();
    }
    #pragma unroll
    for (int n = 0; n < 8; ++n) {
        int col = (n << 4) + (lane & 15);
        float bias = b2a[col];
        int base = ((w * 4 + (col >> 5)) << 9) + (col & 7);
        int chi = ((col & 31) >> 3) << 4;
        #pragma unroll
        for (int jj = 0; jj < 4; ++jj) {
            int rloc = ((lane >> 4) << 2) + jj;
            float hv = acc[n][jj] + bias;
            hv = hv > 0.f ? hv : 0.f;
            Hpack[base + ((rloc | chi) << 3)] = f2bf(hv);
        }
    }
    stage_w(W2b_p, Wbuf[0], tid);
    __syncthreads();
    f32x4 acc2[8];
    #pragma unroll
    for (int n = 0; n < 8; ++n) acc2[n] = (f32x4){0.f, 0.f, 0.f, 0.f};
    for (int kk = 0; kk < 4; ++kk) {
        if (kk < 3) stage_w(W2b_p + (kk + 1) * 4096, Wbuf[(kk + 1) & 1], tid);
        short8 a = *reinterpret_cast<const short8*>(&Hpack[((w * 4 + kk) << 9) + (lane << 3)]);
        const unsigned short* wb = Wbuf[kk & 1];
        #pragma unroll
        for (int n = 0; n < 8; ++n) {
            short8 b = *reinterpret_cast<const short8*>(&wb[((n << 6) + lane) << 3]);
            acc2[n] = __builtin_amdgcn_mfma_f32_16x16x32_bf16(a, b, acc2[n], 0, 0, 0);
        }
        __syncthreads();
    }
    #pragma unroll
    for (int n = 0; n < 8; ++n) {
        int col = (n << 4) + (lane & 15);
        float bias = b2b[col];
        #pragma unroll
        for (int jj = 0; jj < 4; ++jj) {
            int rloc = (w << 4) + ((lane >> 4) << 2) + jj;
            int row = r0 + rloc;
            if (row < O_N) inout[(size_t)row * 128 + col] = acc2[n][jj] + bias;
        }
    }
}

extern "C" void kernel_launch(void* const* d_in, const int* in_sizes, int n_in,
                              void* d_out, int out_size, void* d_ws, size_t ws_size,
                              hipStream_t stream)
{
    const float* obj   = (const float*)d_in[0];
    const float* pred  = (const float*)d_in[1];
    const int*   edges = (const int*)d_in[2];
    const float* W1a = (const float*)d_in[3];
    const float* b1a = (const float*)d_in[4];
    const float* W1b = (const float*)d_in[5];
    const float* b1b = (const float*)d_in[6];
    const float* W2a = (const float*)d_in[7];
    const float* b2a = (const float*)d_in[8];
    const float* W2b = (const float*)d_in[9];
    const float* b2b = (const float*)d_in[10];

    float* out    = (float*)d_out;
    float* new_p  = out + (size_t)O_N * 128;   // T x 128

    uintptr_t wsbase = (uintptr_t)d_ws;
    float* counts = (float*)wsbase;
    uintptr_t p = (wsbase + (size_t)O_N * 4 + 255) & ~(uintptr_t)255;
    ushort_t* pooled_bf = (ushort_t*)p;  p += (size_t)O_N * 128 * 2;   // 25.6 MB
    ushort_t* W1a_p = (ushort_t*)p;  p += (size_t)49152 * 2;
    ushort_t* W1b_p = (ushort_t*)p;  p += (size_t)49152 * 2;
    ushort_t* W2a_p = (ushort_t*)p;  p += (size_t)16384 * 2;
    ushort_t* W2b_p = (ushort_t*)p;  p += (size_t)16384 * 2;
    ushort_t* hbuf  = (ushort_t*)p;  p += (size_t)T_N * 128 * 2;       // 102.4 MB
    size_t need = p - wsbase;

    hipMemsetAsync(counts, 0, (size_t)O_N * sizeof(float), stream);

    if (ws_size >= need) {
        hipMemsetAsync(pooled_bf, 0, (size_t)O_N * 128 * 2, stream);

        pack_b32<<<192, 256, 0, stream>>>(W1a, W1a_p, 24, 4, 128, 0);   // 49152 items
        pack_b32<<<192, 256, 0, stream>>>(W1b, W1b_p, 8, 12, 384, 0);   // 49152 items
        pack_b32<<<64, 256, 0, stream>>>(W2a, W2a_p, 8, 4, 128, 0);     // 16384 items
        pack_b32<<<64, 256, 0, stream>>>(W2b, W2b_p, 8, 4, 128, 0);     // 16384 items

        gemm1_k<<<512, 512, 0, stream>>>(obj, pred, edges, W1a_p, b1a, hbuf, counts);
        gemm2_k<<<512, 512, 0, stream>>>(hbuf, edges, W1b_p, b1b, pooled_bf, new_p);
        objects_k32<<<391, 512, 0, stream>>>(pooled_bf, counts, W2a_p, b2a, W2b_p, b2b, out);
    } else {
        // fallback: round-1 fused path (correct, slower); pooled f32 in d_out
        float* pooled = out;
        hipMemsetAsync(pooled, 0, (size_t)O_N * 128 * sizeof(float), stream);

        pack_b<<<192, 256, 0, stream>>>(W1a, W1a_p, 384, 8, 128, 0);
        pack_b<<<64, 256, 0, stream>>>(W1b, W1b_p,         128, 8, 384, 0);
        pack_b<<<64, 256, 0, stream>>>(W1b, W1b_p + 16384, 128, 8, 384, 128);
        pack_b<<<64, 256, 0, stream>>>(W1b, W1b_p + 32768, 128, 8, 384, 256);
        pack_b<<<64, 256, 0, stream>>>(W2a, W2a_p, 128, 8, 128, 0);
        pack_b<<<64, 256, 0, stream>>>(W2b, W2b_p, 128, 8, 128, 0);

        triples_kernel<<<T_N / 64, 256, 0, stream>>>(obj, pred, edges,
                                                     W1a_p, b1a, W1b_p, b1b,
                                                     pooled, new_p, counts);
        objects_kernel<<<(O_N + 63) / 64, 256, 0, stream>>>(counts, W2a_p, b2a, W2b_p, b2b, out);
    }
}

// Round 5
// 584.368 us; speedup vs baseline: 1.6428x; 1.1467x over previous
//
#include <hip/hip_runtime.h>
#include <hip/hip_bf16.h>
#include <stdint.h>

#define O_N 100000
#define T_N 400000
#define NCH1 1563   // ceil(400000/256) for gemm2
#define NCH1B 6250  // 400000/64 for gemm1
#define NCH3 391    // ceil(100000/256)

typedef __attribute__((ext_vector_type(8))) short short8;
typedef __attribute__((ext_vector_type(4))) unsigned short us4;
typedef __attribute__((ext_vector_type(4))) float f32x4;
typedef __attribute__((ext_vector_type(16))) float f32x16;
typedef unsigned short ushort_t;

__device__ __forceinline__ unsigned short f2bf(float x) {
    union { float f; unsigned u; } v; v.f = x;
    unsigned u = v.u;
    unsigned rounded = u + 0x7FFF + ((u >> 16) & 1);
    return (unsigned short)(rounded >> 16);
}

__device__ __forceinline__ short8 pack8(f32x4 a, f32x4 b) {
    short8 t;
    t[0] = (short)f2bf(a[0]); t[1] = (short)f2bf(a[1]);
    t[2] = (short)f2bf(a[2]); t[3] = (short)f2bf(a[3]);
    t[4] = (short)f2bf(b[0]); t[5] = (short)f2bf(b[1]);
    t[6] = (short)f2bf(b[2]); t[7] = (short)f2bf(b[3]);
    return t;
}

__device__ __forceinline__ us4 pack4(f32x4 a) {
    us4 t;
    t[0] = f2bf(a[0]); t[1] = f2bf(a[1]); t[2] = f2bf(a[2]); t[3] = f2bf(a[3]);
    return t;
}

// ---------------- 32x32x16 path ----------------
// B-fragment pack for mfma_f32_32x32x16_bf16:
// out[((ks*NT+nt)*64+lane)*8+j] = bf16(W[ks*16 + (lane>>5)*8 + j][col0 + nt*32 + (lane&31)])
__global__ void pack_b32(const float* __restrict__ W, ushort_t* __restrict__ out,
                         int Ksteps, int NT, int ldw, int col0) {
    int idx = blockIdx.x * 256 + threadIdx.x;
    int total = Ksteps * NT * 512;
    if (idx >= total) return;
    int j = idx & 7;
    int lane = (idx >> 3) & 63;
    int t2 = idx >> 9;
    int nt = t2 % NT;
    int ks = t2 / NT;
    int k = ks * 16 + ((lane >> 5) << 3) + j;
    int n = col0 + (nt << 5) + (lane & 31);
    out[idx] = f2bf(W[(size_t)k * ldw + n]);
}

// K1 v3: coalesced cooperative gather -> LDS A-tile (fragment layout) + register
// prefetch of next chunk; W1a resident in LDS; h -> hbuf in FRAGMENT-PACKED layout.
// Chunk = 64 triples. 8 waves: wave w -> rows (w&1)*32.., cols (w>>1)*32..
__global__ __launch_bounds__(512, 2) void gemm1_k(
    const float* __restrict__ obj_vecs, const float* __restrict__ pred_vecs,
    const int* __restrict__ edges,
    const ushort_t* __restrict__ W1a_p, const float* __restrict__ b1a,
    ushort_t* __restrict__ hbuf, float* __restrict__ counts)
{
    __shared__ __align__(16) ushort_t Wl[49152];  // 96 KB
    __shared__ __align__(16) ushort_t Ast[24576]; // 48 KB: [g2][ks24][q2][r32][j8]
    const int tid = threadIdx.x;
    const int l = tid & 63;
    const int w = tid >> 6;
    const int q = l >> 5;
    const int r32 = l & 31;
    const int np = w >> 1;   // col tile 0..3
    const int g  = w & 1;    // row half 0..1

    {
        const short8* s = reinterpret_cast<const short8*>(W1a_p);
        short8* d = reinterpret_cast<short8*>(Wl);
        #pragma unroll
        for (int i = 0; i < 12; ++i) d[i * 512 + tid] = s[i * 512 + tid];
    }

    const float bias = b1a[(np << 5) + r32];
    const int2* e2 = (const int2*)edges;

    int c = blockIdx.x;
    f32x4 v[12];
    // prologue: load chunk c (coalesced: 96 consecutive lanes cover one 384-f32 row)
    #pragma unroll
    for (int i = 0; i < 12; ++i) {
        int s = i * 512 + tid;
        int row = s / 96;
        int cc = (s - row * 96) * 4;
        int2 e = e2[c * 64 + row];
        const float* bp = (cc < 128) ? obj_vecs  + (size_t)e.x * 128 + cc
                        : (cc < 256) ? pred_vecs + (size_t)(c * 64 + row) * 128 + (cc - 128)
                                     : obj_vecs  + (size_t)e.y * 128 + (cc - 256);
        v[i] = *reinterpret_cast<const f32x4*>(bp);
    }
    __syncthreads(); // Wl ready

    for (;;) {
        // stage v -> Ast (fragment layout, bf16)
        #pragma unroll
        for (int i = 0; i < 12; ++i) {
            int s = i * 512 + tid;
            int row = s / 96;
            int cc = (s - row * 96) * 4;
            int ks = cc >> 4, q2 = (cc >> 3) & 1, j0 = cc & 7;
            int ad = ((((row >> 5) * 24 + ks) * 2 + q2) * 32 + (row & 31)) * 8 + j0;
            *reinterpret_cast<us4*>(&Ast[ad]) = pack4(v[i]);
        }
        if (tid < 64) {
            int2 e = e2[c * 64 + tid];
            atomicAdd(&counts[e.x], 1.0f);
            atomicAdd(&counts[e.y], 1.0f);
        }
        __syncthreads();

        int cn = c + (int)gridDim.x;
        if (cn < NCH1B) {
            #pragma unroll
            for (int i = 0; i < 12; ++i) {
                int s = i * 512 + tid;
                int row = s / 96;
                int cc = (s - row * 96) * 4;
                int2 e = e2[cn * 64 + row];
                const float* bp = (cc < 128) ? obj_vecs  + (size_t)e.x * 128 + cc
                                : (cc < 256) ? pred_vecs + (size_t)(cn * 64 + row) * 128 + (cc - 128)
                                             : obj_vecs  + (size_t)e.y * 128 + (cc - 256);
                v[i] = *reinterpret_cast<const f32x4*>(bp);
            }
        }

        // compute: 24 MFMA per wave, A from Ast, B from Wl (both conflict-free b128)
        f32x16 acc = {};
        #pragma unroll
        for (int ks = 0; ks < 24; ++ks) {
            short8 a = *reinterpret_cast<const short8*>(&Ast[(((g * 24 + ks) * 2 + q) * 32 + r32) * 8]);
            short8 b = *reinterpret_cast<const short8*>(&Wl[(((ks << 2) + np) * 64 + l) * 8]);
            acc = __builtin_amdgcn_mfma_f32_32x32x16_bf16(a, b, acc, 0, 0, 0);
        }

        // h -> hbuf, fragment-packed: addr = (((t32*8+ks2)*2+q2)*32 + row32)*8 + j2
        {
            int t32 = c * 2 + g;
            int C = (np << 5) + r32;
            int ks2 = C >> 4, q2 = (C >> 3) & 1, j2 = C & 7;
            size_t hb = (size_t)(((t32 * 8 + ks2) * 2 + q2) * 32) * 8 + j2;
            #pragma unroll
            for (int r = 0; r < 16; ++r) {
                int rl = (r & 3) + ((r >> 2) << 3) + (q << 2);
                hbuf[hb + rl * 8] = f2bf(fmaxf(acc[r] + bias, 0.0f));
            }
        }
        __syncthreads(); // Ast consumed
        if (cn >= NCH1B) break;
        c = cn;
    }
}

// K2: h(packed) @ W1b + b1b -> 3 nt-groups: {new_s pk-atomic, new_p store, new_o pk-atomic}.
// W1b resident in LDS; pooled accumulated as bf16 via global_atomic_pk_add_bf16.
__global__ __launch_bounds__(512, 2) void gemm2_k(
    const ushort_t* __restrict__ hbuf, const int* __restrict__ edges,
    const ushort_t* __restrict__ W1b_p, const float* __restrict__ b1b,
    ushort_t* __restrict__ pooled_bf, float* __restrict__ new_p)
{
    __shared__ __align__(16) ushort_t Wl[49152]; // 96 KB
    const int tid = threadIdx.x;
    const int l = tid & 63;
    const int w = tid >> 6;
    const int q = l >> 5;
    const int r32 = l & 31;

    {
        const short8* s = reinterpret_cast<const short8*>(W1b_p);
        short8* d = reinterpret_cast<short8*>(Wl);
        #pragma unroll
        for (int i = 0; i < 12; ++i) d[i * 512 + tid] = s[i * 512 + tid];
    }
    __syncthreads();

    float bias[12];
    #pragma unroll
    for (int nt = 0; nt < 12; ++nt) bias[nt] = b1b[(nt << 5) + r32];

    for (int c = blockIdx.x; c < NCH1; c += gridDim.x) {
        int t32g = c * 8 + w;
        if (t32g > T_N / 32 - 1) t32g = T_N / 32 - 1;

        // packed, perfectly coalesced A-fragment loads
        short8 af[8];
        #pragma unroll
        for (int ks = 0; ks < 8; ++ks)
            af[ks] = *reinterpret_cast<const short8*>(
                &hbuf[(size_t)(((t32g * 8 + ks) * 2 + q) * 32 + r32) * 8]);

        #pragma unroll
        for (int g = 0; g < 3; ++g) {
            f32x16 acc[4] = {};
            #pragma unroll
            for (int ks = 0; ks < 8; ++ks) {
                #pragma unroll
                for (int nt2 = 0; nt2 < 4; ++nt2) {
                    short8 bf = *reinterpret_cast<const short8*>(&Wl[((ks * 12 + (g << 2) + nt2) * 64 + l) * 8]);
                    acc[nt2] = __builtin_amdgcn_mfma_f32_32x32x16_bf16(af[ks], bf, acc[nt2], 0, 0, 0);
                }
            }
            if (g == 1) {
                #pragma unroll
                for (int nt2 = 0; nt2 < 4; ++nt2) {
                    #pragma unroll
                    for (int r = 0; r < 16; ++r) {
                        int rl = (r & 3) + ((r >> 2) << 3) + (q << 2);
                        int trow2 = c * 256 + w * 32 + rl;
                        if (trow2 < T_N)
                            new_p[(size_t)trow2 * 128 + (nt2 << 5) + r32] = acc[nt2][r] + bias[4 + nt2];
                    }
                }
            } else {
                #pragma unroll
                for (int r = 0; r < 16; ++r) {
                    int rl = (r & 3) + ((r >> 2) << 3) + (q << 2);
                    int trow2 = c * 256 + w * 32 + rl;
                    bool v2 = trow2 < T_N;
                    int t2 = v2 ? trow2 : T_N - 1;
                    int2 e2 = ((const int2*)edges)[t2];
                    int seg = (g == 0) ? e2.x : e2.y;
                    ushort_t* pb = pooled_bf + (size_t)seg * 128;
                    #pragma unroll
                    for (int nt2 = 0; nt2 < 4; ++nt2) {
                        float val = acc[nt2][r] + bias[(g << 2) + nt2];
                        float other = __shfl_xor(val, 1, 64);
                        if (v2 && !(r32 & 1)) {
                            unsigned dat = (unsigned)f2bf(val) | ((unsigned)f2bf(other) << 16);
                            uint64_t addr = (uint64_t)(uintptr_t)(pb + (nt2 << 5) + r32);
                            asm volatile("global_atomic_pk_add_bf16 %0, %1, off"
                                         :: "v"(addr), "v"(dat) : "memory");
                        }
                    }
                }
            }
        }
    }
}

// K3: pooled_bf/counts -> relu(x@W2a+b2a)@W2b+b2b -> new_obj (f32, d_out).
__global__ __launch_bounds__(512, 2) void objects_k32(
    const ushort_t* __restrict__ pooled_bf, const float* __restrict__ counts,
    const ushort_t* __restrict__ W2a_p, const float* __restrict__ b2a,
    const ushort_t* __restrict__ W2b_p, const float* __restrict__ b2b,
    float* __restrict__ outp)
{
    __shared__ __align__(16) ushort_t Wa[16384];   // 32 KB
    __shared__ __align__(16) ushort_t Wb[16384];   // 32 KB
    __shared__ __align__(16) ushort_t hx[8][4096]; // 64 KB, per-wave swizzled exchange
    const int tid = threadIdx.x;
    const int l = tid & 63;
    const int w = tid >> 6;
    const int q = l >> 5;
    const int r32 = l & 31;

    {
        const short8* sa = reinterpret_cast<const short8*>(W2a_p);
        const short8* sb = reinterpret_cast<const short8*>(W2b_p);
        short8* da = reinterpret_cast<short8*>(Wa);
        short8* db = reinterpret_cast<short8*>(Wb);
        #pragma unroll
        for (int i = 0; i < 4; ++i) { da[i * 512 + tid] = sa[i * 512 + tid]; db[i * 512 + tid] = sb[i * 512 + tid]; }
    }
    __syncthreads();

    float ba[4], bb[4];
    #pragma unroll
    for (int nt = 0; nt < 4; ++nt) { ba[nt] = b2a[(nt << 5) + r32]; bb[nt] = b2b[(nt << 5) + r32]; }

    for (int c = blockIdx.x; c < NCH3; c += gridDim.x) {
        int row = c * 256 + w * 32 + r32;
        int rr = row < O_N ? row : O_N - 1;
        float inv = 1.0f / fmaxf(counts[rr], 1.0f);

        short8 af[8];
        #pragma unroll
        for (int ks = 0; ks < 8; ++ks) {
            short8 raw = *reinterpret_cast<const short8*>(&pooled_bf[(size_t)rr * 128 + (ks << 4) + (q << 3)]);
            short8 a;
            #pragma unroll
            for (int j = 0; j < 8; ++j) {
                union { float f; unsigned u; } t;
                t.u = ((unsigned)(unsigned short)raw[j]) << 16;
                a[j] = (short)f2bf(t.f * inv);
            }
            af[ks] = a;
        }

        f32x16 acc[4] = {};
        #pragma unroll
        for (int ks = 0; ks < 8; ++ks) {
            #pragma unroll
            for (int nt = 0; nt < 4; ++nt) {
                short8 bf = *reinterpret_cast<const short8*>(&Wa[(((ks << 2) + nt) * 64 + l) * 8]);
                acc[nt] = __builtin_amdgcn_mfma_f32_32x32x16_bf16(af[ks], bf, acc[nt], 0, 0, 0);
            }
        }

        // h -> per-wave LDS (XOR-swizzled rows to avoid conflicts on b128 reads)
        char* hxw = (char*)&hx[w][0];
        #pragma unroll
        for (int nt = 0; nt < 4; ++nt) {
            #pragma unroll
            for (int r = 0; r < 16; ++r) {
                int rl = (r & 3) + ((r >> 2) << 3) + (q << 2);
                float hv = fmaxf(acc[nt][r] + ba[nt], 0.0f);
                int off = rl * 256 + (((nt << 5) + r32) << 1);
                off ^= (rl & 15) << 4;
                *(ushort_t*)(hxw + off) = f2bf(hv);
            }
        }
        __syncthreads();

        short8 af2[8];
        #pragma unroll
        for (int ks = 0; ks < 8; ++ks) {
            int off = r32 * 256 + (ks << 5) + (q << 4);
            off ^= (r32 & 15) << 4;
            af2[ks] = *reinterpret_cast<const short8*>(hxw + off);
        }

        f32x16 acc2[4] = {};
        #pragma unroll
        for (int ks = 0; ks < 8; ++ks) {
            #pragma unroll
            for (int nt = 0; nt < 4; ++nt) {
                short8 bf = *reinterpret_cast<const short8*>(&Wb[(((ks << 2) + nt) * 64 + l) * 8]);
                acc2[nt] = __builtin_amdgcn_mfma_f32_32x32x16_bf16(af2[ks], bf, acc2[nt], 0, 0, 0);
            }
        }

        #pragma unroll
        for (int nt = 0; nt < 4; ++nt) {
            #pragma unroll
            for (int r = 0; r < 16; ++r) {
                int rl = (r & 3) + ((r >> 2) << 3) + (q << 2);
                int row2 = c * 256 + w * 32 + rl;
                if (row2 < O_N) outp[(size_t)row2 * 128 + (nt << 5) + r32] = acc2[nt][r] + bb[nt];
            }
        }
        __syncthreads();
    }
}

// ---------------- fallback path (round-1, 16x16x32, known-good) ----------------
__global__ void pack_b(const float* __restrict__ W, unsigned short* __restrict__ out,
                       int K, int Ntiles, int ldw, int col0) {
    int idx = blockIdx.x * 256 + threadIdx.x;
    int total = K * Ntiles * 16;
    if (idx >= total) return;
    int j = idx & 7;
    int lane = (idx >> 3) & 63;
    int t2 = idx >> 9;
    int ntile = t2 % Ntiles;
    int kstep = t2 / Ntiles;
    int k = kstep * 32 + ((lane >> 4) << 3) + j;
    int n = (ntile << 4) + (lane & 15);
    out[idx] = f2bf(W[(size_t)k * ldw + col0 + n]);
}

__device__ __forceinline__ void stage_w(const unsigned short* __restrict__ src,
                                        unsigned short* __restrict__ dst, int tid) {
    const short8* s = reinterpret_cast<const short8*>(src);
    short8* d = reinterpret_cast<short8*>(dst);
    d[tid] = s[tid];
    d[tid + 256] = s[tid + 256];
}

__global__ __launch_bounds__(256, 2) void triples_kernel(
    const float* __restrict__ obj_vecs, const float* __restrict__ pred_vecs,
    const int* __restrict__ edges,
    const unsigned short* __restrict__ W1a_p, const float* __restrict__ b1a,
    const unsigned short* __restrict__ W1b_p, const float* __restrict__ b1b,
    float* __restrict__ pooled, float* __restrict__ new_p, float* __restrict__ counts)
{
    __shared__ __align__(16) unsigned short Apack[24576];
    __shared__ __align__(16) unsigned short Wbuf[2][4096];
    __shared__ int sseg[64], oseg[64];
    const int tid = threadIdx.x;
    const int lane = tid & 63;
    const int w = tid >> 6;
    const int t0 = blockIdx.x * 64;
    if (tid < 64) {
        int s = edges[2 * (t0 + tid)];
        int o = edges[2 * (t0 + tid) + 1];
        sseg[tid] = s; oseg[tid] = o;
        atomicAdd(&counts[s], 1.0f);
        atomicAdd(&counts[o], 1.0f);
    }
    __syncthreads();
    for (int it = 0; it < 24; ++it) {
        int idx = it * 256 + tid;
        int r = idx / 96;
        int c = (idx % 96) * 4;
        const float* srcp;
        if (c < 128)      srcp = obj_vecs  + (size_t)sseg[r] * 128 + c;
        else if (c < 256) srcp = pred_vecs + (size_t)(t0 + r) * 128 + (c - 128);
        else              srcp = obj_vecs  + (size_t)oseg[r] * 128 + (c - 256);
        f32x4 v = *reinterpret_cast<const f32x4*>(srcp);
        int off = (((r >> 4) * 12 + (c >> 5)) << 9)
                + (((r & 15) | (((c & 31) >> 3) << 4)) << 3) + (c & 7);
        Apack[off + 0] = f2bf(v[0]); Apack[off + 1] = f2bf(v[1]);
        Apack[off + 2] = f2bf(v[2]); Apack[off + 3] = f2bf(v[3]);
    }
    stage_w(W1a_p, Wbuf[0], tid);
    __syncthreads();
    f32x4 acc[8];
    #pragma unroll
    for (int n = 0; n < 8; ++n) acc[n] = (f32x4){0.f, 0.f, 0.f, 0.f};
    for (int kk = 0; kk < 12; ++kk) {
        if (kk < 11) stage_w(W1a_p + (kk + 1) * 4096, Wbuf[(kk + 1) & 1], tid);
        short8 a = *reinterpret_cast<const short8*>(&Apack[((w * 12 + kk) << 9) + (lane << 3)]);
        const unsigned short* wb = Wbuf[kk & 1];
        #pragma unroll
        for (int n = 0; n < 8; ++n) {
            short8 b = *reinterpret_cast<const short8*>(&wb[((n << 6) + lane) << 3]);
            acc[n] = __builtin_amdgcn_mfma_f32_16x16x32_bf16(a, b, acc[n], 0, 0, 0);
        }
        __syncthreads();
    }
    #pragma unroll
    for (int n = 0; n < 8; ++n) {
        int col = (n << 4) + (lane & 15);
        float bias = b1a[col];
        int base = ((w * 4 + (col >> 5)) << 9) + (col & 7);
        int chi = ((col & 31) >> 3) << 4;
        #pragma unroll
        for (int jj = 0; jj < 4; ++jj) {
            int rloc = ((lane >> 4) << 2) + jj;
            float hv = acc[n][jj] + bias;
            hv = hv > 0.f ? hv : 0.f;
            Apack[base + ((rloc | chi) << 3)] = f2bf(hv);
        }
    }
    for (int g = 0; g < 3; ++g) {
        const unsigned short* Wsrc = W1b_p + g * 16384;
        stage_w(Wsrc, Wbuf[0], tid);
        __syncthreads();
        f32x4 acc2[8];
        #pragma unroll
        for (int n = 0; n < 8; ++n) acc2[n] = (f32x4){0.f, 0.f, 0.f, 0.f};
        for (int kk = 0; kk < 4; ++kk) {
            if (kk < 3) stage_w(Wsrc + (kk + 1) * 4096, Wbuf[(kk + 1) & 1], tid);
            short8 a = *reinterpret_cast<const short8*>(&Apack[((w * 4 + kk) << 9) + (lane << 3)]);
            const unsigned short* wb = Wbuf[kk & 1];
            #pragma unroll
            for (int n = 0; n < 8; ++n) {
                short8 b = *reinterpret_cast<const short8*>(&wb[((n << 6) + lane) << 3]);
                acc2[n] = __builtin_amdgcn_mfma_f32_16x16x32_bf16(a, b, acc2[n], 0, 0, 0);
            }
            __syncthreads();
        }
        #pragma unroll
        for (int n = 0; n < 8; ++n) {
            int col = (n << 4) + (lane & 15);
            float bias = b1b[g * 128 + col];
            #pragma unroll
            for (int jj = 0; jj < 4; ++jj) {
                int rloc = (w << 4) + ((lane >> 4) << 2) + jj;
                float val = acc2[n][jj] + bias;
                if (g == 1) {
                    new_p[(size_t)(t0 + rloc) * 128 + col] = val;
                } else {
                    int seg = (g == 0) ? sseg[rloc] : oseg[rloc];
                    atomicAdd(&pooled[(size_t)seg * 128 + col], val);
                }
            }
        }
    }
}

__global__ __launch_bounds__(256, 2) void objects_kernel(
    const float* __restrict__ counts,
    const unsigned short* __restrict__ W2a_p, const float* __restrict__ b2a,
    const unsigned short* __restrict__ W2b_p, const float* __restrict__ b2b,
    float* __restrict__ inout)
{
    __shared__ __align__(16) unsigned short Apack[8192];
    __shared__ __align__(16) unsigned short Hpack[8192];
    __shared__ __align__(16) unsigned short Wbuf[2][4096];
    const int tid = threadIdx.x;
    const int lane = tid & 63;
    const int w = tid >> 6;
    const int r0 = blockIdx.x * 64;
    for (int it = 0; it < 8; ++it) {
        int idx = it * 256 + tid;
        int r = idx >> 5;
        int c = (idx & 31) << 2;
        int row = r0 + r;
        float vals[4] = {0.f, 0.f, 0.f, 0.f};
        if (row < O_N) {
            f32x4 v = *reinterpret_cast<const f32x4*>(&inout[(size_t)row * 128 + c]);
            float inv = 1.0f / fmaxf(counts[row], 1.0f);
            vals[0] = v[0] * inv; vals[1] = v[1] * inv;
            vals[2] = v[2] * inv; vals[3] = v[3] * inv;
        }
        int off = (((r >> 4) * 4 + (c >> 5)) << 9)
                + (((r & 15) | (((c & 31) >> 3) << 4)) << 3) + (c & 7);
        Apack[off + 0] = f2bf(vals[0]); Apack[off + 1] = f2bf(vals[1]);
        Apack[off + 2] = f2bf(vals[2]); Apack[off + 3] = f2bf(vals[3]);
    }
    stage_w(W2a_p, Wbuf[0], tid);
    __syncthreads();
    f32x4 acc[8];
    #pragma unroll
    for (int n = 0; n < 8; ++n) acc[n] = (f32x4){0.f, 0.f, 0.f, 0.f};
    for (int kk = 0; kk < 4; ++kk) {
        if (kk < 3) stage_w(W2a_p + (kk + 1) * 4096, Wbuf[(kk + 1) & 1], tid);
        short8 a = *reinterpret_cast<const short8*>(&Apack[((w * 4 + kk) << 9) + (lane << 3)]);
        const unsigned short* wb = Wbuf[kk & 1];
        #pragma unroll
        for (int n = 0; n < 8; ++n) {
            short8 b = *reinterpret_cast<const short8*>(&wb[((n << 6) + lane) << 3]);
            acc[n] = __builtin_amdgcn_mfma_f32_16x16x32_bf16(a, b, acc[n], 0, 0, 0);
        }
        __syncthreads();
    }
    #pragma unroll
    for (int n = 0; n < 8; ++n) {
        int col = (n << 4) + (lane & 15);
        float bias = b2a[col];
        int base = ((w * 4 + (col >> 5)) << 9) + (col & 7);
        int chi = ((col & 31) >> 3) << 4;
        #pragma unroll
        for (int jj = 0; jj < 4; ++jj) {
            int rloc = ((lane >> 4) << 2) + jj;
            float hv = acc[n][jj] + bias;
            hv = hv > 0.f ? hv : 0.f;
            Hpack[base + ((rloc | chi) << 3)] = f2bf(hv);
        }
    }
    stage_w(W2b_p, Wbuf[0], tid);
    __syncthreads();
    f32x4 acc2[8];
    #pragma unroll
    for (int n = 0; n < 8; ++n) acc2[n] = (f32x4){0.f, 0.f, 0.f, 0.f};
    for (int kk = 0; kk < 4; ++kk) {
        if (kk < 3) stage_w(W2b_p + (kk + 1) * 4096, Wbuf[(kk + 1) & 1], tid);
        short8 a = *reinterpret_cast<const short8*>(&Hpack[((w * 4 + kk) << 9) + (lane << 3)]);
        const unsigned short* wb = Wbuf[kk & 1];
        #pragma unroll
        for (int n = 0; n < 8; ++n) {
            short8 b = *reinterpret_cast<const short8*>(&wb[((n << 6) + lane) << 3]);
            acc2[n] = __builtin_amdgcn_mfma_f32_16x16x32_bf16(a, b, acc2[n], 0, 0, 0);
        }
        __syncthreads();
    }
    #pragma unroll
    for (int n = 0; n < 8; ++n) {
        int col = (n << 4) + (lane & 15);
        float bias = b2b[col];
        #pragma unroll
        for (int jj = 0; jj < 4; ++jj) {
            int rloc = (w << 4) + ((lane >> 4) << 2) + jj;
            int row = r0 + rloc;
            if (row < O_N) inout[(size_t)row * 128 + col] = acc2[n][jj] + bias;
        }
    }
}

extern "C" void kernel_launch(void* const* d_in, const int* in_sizes, int n_in,
                              void* d_out, int out_size, void* d_ws, size_t ws_size,
                              hipStream_t stream)
{
    const float* obj   = (const float*)d_in[0];
    const float* pred  = (const float*)d_in[1];
    const int*   edges = (const int*)d_in[2];
    const float* W1a = (const float*)d_in[3];
    const float* b1a = (const float*)d_in[4];
    const float* W1b = (const float*)d_in[5];
    const float* b1b = (const float*)d_in[6];
    const float* W2a = (const float*)d_in[7];
    const float* b2a = (const float*)d_in[8];
    const float* W2b = (const float*)d_in[9];
    const float* b2b = (const float*)d_in[10];

    float* out    = (float*)d_out;
    float* new_p  = out + (size_t)O_N * 128;   // T x 128

    uintptr_t wsbase = (uintptr_t)d_ws;
    float* counts = (float*)wsbase;
    uintptr_t p = (wsbase + (size_t)O_N * 4 + 255) & ~(uintptr_t)255;
    ushort_t* pooled_bf = (ushort_t*)p;  p += (size_t)O_N * 128 * 2;   // 25.6 MB
    ushort_t* W1a_p = (ushort_t*)p;  p += (size_t)49152 * 2;
    ushort_t* W1b_p = (ushort_t*)p;  p += (size_t)49152 * 2;
    ushort_t* W2a_p = (ushort_t*)p;  p += (size_t)16384 * 2;
    ushort_t* W2b_p = (ushort_t*)p;  p += (size_t)16384 * 2;
    ushort_t* hbuf  = (ushort_t*)p;  p += (size_t)T_N * 128 * 2;       // 102.4 MB (fragment-packed)
    size_t need = p - wsbase;

    hipMemsetAsync(counts, 0, (size_t)O_N * sizeof(float), stream);

    if (ws_size >= need) {
        hipMemsetAsync(pooled_bf, 0, (size_t)O_N * 128 * 2, stream);

        pack_b32<<<192, 256, 0, stream>>>(W1a, W1a_p, 24, 4, 128, 0);   // 49152 items
        pack_b32<<<192, 256, 0, stream>>>(W1b, W1b_p, 8, 12, 384, 0);   // 49152 items
        pack_b32<<<64, 256, 0, stream>>>(W2a, W2a_p, 8, 4, 128, 0);     // 16384 items
        pack_b32<<<64, 256, 0, stream>>>(W2b, W2b_p, 8, 4, 128, 0);     // 16384 items

        gemm1_k<<<256, 512, 0, stream>>>(obj, pred, edges, W1a_p, b1a, hbuf, counts);
        gemm2_k<<<256, 512, 0, stream>>>(hbuf, edges, W1b_p, b1b, pooled_bf, new_p);
        objects_k32<<<391, 512, 0, stream>>>(pooled_bf, counts, W2a_p, b2a, W2b_p, b2b, out);
    } else {
        // fallback: round-1 fused path (correct, slower); pooled f32 in d_out
        float* pooled = out;
        hipMemsetAsync(pooled, 0, (size_t)O_N * 128 * sizeof(float), stream);

        pack_b<<<192, 256, 0, stream>>>(W1a, W1a_p, 384, 8, 128, 0);
        pack_b<<<64, 256, 0, stream>>>(W1b, W1b_p,         128, 8, 384, 0);
        pack_b<<<64, 256, 0, stream>>>(W1b, W1b_p + 16384, 128, 8, 384, 128);
        pack_b<<<64, 256, 0, stream>>>(W1b, W1b_p + 32768, 128, 8, 384, 256);
        pack_b<<<64, 256, 0, stream>>>(W2a, W2a_p, 128, 8, 128, 0);
        pack_b<<<64, 256, 0, stream>>>(W2b, W2b_p, 128, 8, 128, 0);

        triples_kernel<<<T_N / 64, 256, 0, stream>>>(obj, pred, edges,
                                                     W1a_p, b1a, W1b_p, b1b,
                                                     pooled, new_p, counts);
        objects_kernel<<<(O_N + 63) / 64, 256, 0, stream>>>(counts, W2a_p, b2a, W2b_p, b2b, out);
    }
}